// Round 5
// baseline (471.573 us; speedup 1.0000x reference)
//
#include <hip/hip_runtime.h>
#include <hip/hip_bf16.h>
#include <stdint.h>

// ---------------------------------------------------------------------------
// RG-LRU block: T=8192, D_MODEL=768, D_RNN=1024, KW=4.
// Round 5: BARRIER-FREE K-loop (AITER-style).
//  - Each wave stages its own 64x32 A and B slices into wave-PRIVATE LDS
//    double buffers -> zero __syncthreads in the GEMM.
//  - Manual s_waitcnt vmcnt(8) (imm 0x0F78): after issuing the 8 next-tile
//    global_load_lds, wait only for the 8 OLDER ones (vmcnt is issue-ordered).
//    Prefetch stays in flight across the whole compute phase; waves slip
//    independently -> latency hidden without barrier convergence.
//  - r3's XCD-aware grid kept; r4's prep fusion + bf16 g_pre kept.
//  - LDS XOR swizzle dropped (r4 proved b128 conflicts were not on the
//    critical path; wave-private row-major layout is conflict-minimal).
// ---------------------------------------------------------------------------

#define T_LEN 8192
#define DM 768
#define DR 1024
#define NC 128   // scan chunks
#define CL 64    // chunk length

typedef __bf16 bf16x8 __attribute__((ext_vector_type(8)));
typedef float  f32x4  __attribute__((ext_vector_type(4)));

#define AS1 __attribute__((address_space(1)))
#define AS3 __attribute__((address_space(3)))

// s_waitcnt immediates (gfx9 encoding): vm[3:0]|[15:14], exp[6:4], lgkm[11:8]
#define WAITCNT_VM8 0x0F78   // vmcnt(8), lgkm/exp don't-care
#define WAITCNT_VM0 0x0F70   // vmcnt(0), lgkm/exp don't-care

__device__ __forceinline__ void cp16_g2l(const void* g, void* l) {
    __builtin_amdgcn_global_load_lds((const AS1 void*)g, (AS3 void*)l, 16, 0, 0);
}

__device__ __forceinline__ float gelu_tanh(float x) {
    const float inner = 0.7978845608028654f * (x + 0.044715f * x * x * x);
    return 0.5f * x * (1.f + tanhf(inner));
}

// C[m,n] = sum_k A[m,k]*B[n,k] (+ bias[n]).  A: M x K bf16 row-major (lda),
// B: N x K bf16 row-major.  K must be a multiple of 64 (768/1024/4096 all are).
// CONV: logical A[m,k] = bbp[m + (k>>10)][k & 1023] (bbp = 3-zero-row-padded bb).
// EPI: 0 = fp32 (+bias) -> Cv(float*, ld N)
//      1 = bf16 (+bias if non-null) -> Cv(bf16*, ld N)
//      2 = split: n<1024 -> Cv=bf16(gelu(v+bias)); n>=1024 -> D2[(m+3),n-1024]=bf16(v+bias)
template<bool CONV, int EPI>
__global__ __launch_bounds__(256)
void gemm_mfma(const __hip_bfloat16* __restrict__ A,
               const __hip_bfloat16* __restrict__ B,
               const float* __restrict__ bias,
               void* __restrict__ Cv,
               int K, int lda, int N,
               __hip_bfloat16* __restrict__ D2)
{
    // wave-private: [wave][buf][ A: 0..2047 | B: 2048..4095 ]  (64 KB total)
    __shared__ __bf16 ldsbuf[4][2][4096];

    const int tid  = threadIdx.x;
    const int lane = tid & 63;
    const int wave = tid >> 6;
    const size_t m0 = (size_t)blockIdx.x * 128;   // M-block (XCD = blockIdx.x % 8)
    const int    n0 = blockIdx.y * 128;
    const int wm = (wave >> 1) * 64;
    const int wn = (wave & 1) * 64;

    __bf16* L0 = ldsbuf[wave][0];
    __bf16* L1 = ldsbuf[wave][1];

    // staging: instr j covers rows j*16..j*16+15 of the wave's 64-row slice;
    // lane i -> row j*16 + (i>>2), 16B chunk (i&3).  LDS dest = base + j*1024
    // + lane*16 bytes (wave-uniform base + lane*16: HW requirement met).
    const int srow = lane >> 2;
    const int sch  = (lane & 3) * 8;   // element offset within the 32-wide k-slice
    const __hip_bfloat16* Abase = A + (m0 + wm + srow) * (size_t)lda + sch;
    const __hip_bfloat16* Bbase = B + (size_t)(n0 + wn + srow) * K + sch;

    f32x4 acc[4][4];
#pragma unroll
    for (int i = 0; i < 4; ++i)
#pragma unroll
        for (int j = 0; j < 4; ++j)
            acc[i][j] = f32x4{0.f, 0.f, 0.f, 0.f};

    const int frow = lane & 15;
    const int fq   = lane >> 4;

    // 8 global_load_lds per call (4 A + 4 B)
    auto stage = [&](int k0, __bf16* Lb) {
        const int ksh  = CONV ? (k0 >> 10) : 0;
        const int kcol = CONV ? (k0 & 1023) : k0;
        const __hip_bfloat16* as = Abase + (size_t)ksh * lda + kcol;
        const __hip_bfloat16* bs = Bbase + k0;
#pragma unroll
        for (int j = 0; j < 4; ++j)
            cp16_g2l(as + (size_t)(j * 16) * lda, Lb + j * 512 + lane * 8);
#pragma unroll
        for (int j = 0; j < 4; ++j)
            cp16_g2l(bs + (size_t)(j * 16) * K, Lb + 2048 + j * 512 + lane * 8);
    };

    auto compute = [&](const __bf16* Lb) {
        bf16x8 af[4], bfr[4];
#pragma unroll
        for (int mi = 0; mi < 4; ++mi)
            af[mi] = *(const bf16x8*)(Lb + (mi * 16 + frow) * 32 + fq * 8);
#pragma unroll
        for (int ni = 0; ni < 4; ++ni)
            bfr[ni] = *(const bf16x8*)(Lb + 2048 + (ni * 16 + frow) * 32 + fq * 8);
#pragma unroll
        for (int mi = 0; mi < 4; ++mi)
#pragma unroll
            for (int ni = 0; ni < 4; ++ni)
                acc[mi][ni] = __builtin_amdgcn_mfma_f32_16x16x32_bf16(
                    af[mi], bfr[ni], acc[mi][ni], 0, 0, 0);
    };

    // ---- barrier-free double-buffered K-loop ----
    stage(0, L0);
    int k0 = 0;
    for (; k0 < K - 64; k0 += 64) {
        stage(k0 + 32, L1);
        __builtin_amdgcn_s_waitcnt(WAITCNT_VM8);   // 8 older (L0's) done
        compute(L0);
        stage(k0 + 64, L0);
        __builtin_amdgcn_s_waitcnt(WAITCNT_VM8);   // L1's done
        compute(L1);
    }
    stage(k0 + 32, L1);
    __builtin_amdgcn_s_waitcnt(WAITCNT_VM8);
    compute(L0);
    __builtin_amdgcn_s_waitcnt(WAITCNT_VM0);
    compute(L1);

    // C/D layout: col = lane&15, row = (lane>>4)*4 + reg
    const int er = fq * 4;
    const int ec = frow;
#pragma unroll
    for (int ni = 0; ni < 4; ++ni) {
        const int n = n0 + wn + ni * 16 + ec;
        const float bv = bias ? bias[n] : 0.f;
#pragma unroll
        for (int mi = 0; mi < 4; ++mi) {
#pragma unroll
            for (int r2 = 0; r2 < 4; ++r2) {
                const size_t m = m0 + wm + mi * 16 + er + r2;
                const float v = acc[mi][ni][r2] + bv;
                if (EPI == 0) {
                    ((float*)Cv)[m * (size_t)N + n] = v;
                } else if (EPI == 1) {
                    ((__hip_bfloat16*)Cv)[m * (size_t)N + n] = __float2bfloat16(v);
                } else {
                    if (n < 1024)
                        ((__hip_bfloat16*)Cv)[m * 1024 + n] = __float2bfloat16(gelu_tanh(v));
                    else
                        D2[(m + 3) * 1024 + (n - 1024)] = __float2bfloat16(v);
                }
            }
        }
    }
}

// One prep kernel: xb, w1b, w_rgb, w_outb conversions + conv repack + bbp pad zero.
#define PREP_X   6291456            // 8192*768
#define PREP_W1  (PREP_X + 1572864) // + 2048*768
#define PREP_WRG (PREP_W1 + 2097152)// + 2048*1024
#define PREP_WO  (PREP_WRG + 786432)// + 768*1024
#define PREP_CW  (PREP_WO + 4194304)// + 1024*4096
#define PREP_TOT (PREP_CW + 3072)   // + pad rows
__global__ void prep_kernel(const float* __restrict__ x, const float* __restrict__ w1,
                            const float* __restrict__ w_rg, const float* __restrict__ w_out,
                            const float* __restrict__ conv_w,
                            __hip_bfloat16* __restrict__ xb, __hip_bfloat16* __restrict__ w1b,
                            __hip_bfloat16* __restrict__ w_rgb, __hip_bfloat16* __restrict__ w_outb,
                            __hip_bfloat16* __restrict__ wbigb, __hip_bfloat16* __restrict__ bbp)
{
    const int idx = blockIdx.x * 256 + threadIdx.x;
    if (idx < PREP_X) {
        xb[idx] = __float2bfloat16(x[idx]);
    } else if (idx < PREP_W1) {
        const int i = idx - PREP_X;  w1b[i] = __float2bfloat16(w1[i]);
    } else if (idx < PREP_WRG) {
        const int i = idx - PREP_W1; w_rgb[i] = __float2bfloat16(w_rg[i]);
    } else if (idx < PREP_WO) {
        const int i = idx - PREP_WRG; w_outb[i] = __float2bfloat16(w_out[i]);
    } else if (idx < PREP_CW) {
        const int n = idx - PREP_WO;
        const int o = n >> 12, r = n & 4095, k = r >> 10, i = r & 1023;
        wbigb[n] = __float2bfloat16(conv_w[o * 4096 + i * 4 + k]);
    } else {
        bbp[idx - PREP_CW] = __float2bfloat16(0.f);
    }
}

// Gates recomputed inline from g_pre (T x 2048 bf16) + bc (bf16):
__global__ void scan_pass1(const __hip_bfloat16* __restrict__ gp,
                           const __hip_bfloat16* __restrict__ bc,
                           const float* __restrict__ Lambda,
                           float* __restrict__ ch, float* __restrict__ ca)
{
    const int c = blockIdx.y * 256 + threadIdx.x;
    const int j = blockIdx.x;
    const float cl = -8.f * log1pf(expf(Lambda[c]));
    float h = 0.f, ap = 1.f;
    const int t0 = j * CL;
    for (int tt = 0; tt < CL; ++tt) {
        const int t = t0 + tt;
        const long gi = (long)t * 2048 + c;
        const float ig = 1.f / (1.f + expf(-__bfloat162float(gp[gi])));
        const float rg = 1.f / (1.f + expf(-__bfloat162float(gp[gi + 1024])));
        const float a  = expf(cl * rg);
        const float gx = sqrtf(fmaxf(0.f, 1.f - a * a)) * ig *
                         __bfloat162float(bc[(long)t * 1024 + c]);
        h  = fmaf(a, h, gx);
        ap *= a;
    }
    ch[j * 1024 + c] = h;
    ca[j * 1024 + c] = ap;
}

__global__ void scan_combine(float* __restrict__ ch, const float* __restrict__ ca)
{
    const int c = blockIdx.x * 256 + threadIdx.x;
    float carry = 0.f;
    for (int j = 0; j < NC; ++j) {
        const float hj = ch[j * 1024 + c];
        const float aj = ca[j * 1024 + c];
        ch[j * 1024 + c] = carry;
        carry = fmaf(aj, carry, hj);
    }
}

// Rescan with carry; z = ab * y -> bf16 (zb aliases bc: same-element RMW per thread).
__global__ void scan_pass2(const __hip_bfloat16* __restrict__ gp, const __hip_bfloat16* bc,
                           const float* __restrict__ Lambda,
                           const float* __restrict__ carry_in,
                           const __hip_bfloat16* __restrict__ ab,
                           __hip_bfloat16* zb)
{
    const int c = blockIdx.y * 256 + threadIdx.x;
    const int j = blockIdx.x;
    const float cl = -8.f * log1pf(expf(Lambda[c]));
    float h = carry_in[j * 1024 + c];
    const int t0 = j * CL;
    for (int tt = 0; tt < CL; ++tt) {
        const int t = t0 + tt;
        const long gi = (long)t * 2048 + c;
        const long bi = (long)t * 1024 + c;
        const float ig = 1.f / (1.f + expf(-__bfloat162float(gp[gi])));
        const float rg = 1.f / (1.f + expf(-__bfloat162float(gp[gi + 1024])));
        const float a  = expf(cl * rg);
        const float gx = sqrtf(fmaxf(0.f, 1.f - a * a)) * ig * __bfloat162float(bc[bi]);
        h = fmaf(a, h, gx);
        zb[bi] = __float2bfloat16(__bfloat162float(ab[bi]) * h);
    }
}

extern "C" void kernel_launch(void* const* d_in, const int* in_sizes, int n_in,
                              void* d_out, int out_size, void* d_ws, size_t ws_size,
                              hipStream_t stream)
{
    const float* x      = (const float*)d_in[0];
    const float* w1     = (const float*)d_in[1];
    const float* b1     = (const float*)d_in[2];
    const float* conv_w = (const float*)d_in[3];
    const float* w_rg   = (const float*)d_in[4];
    const float* b_rg   = (const float*)d_in[5];
    const float* w_out  = (const float*)d_in[6];
    const float* b_out  = (const float*)d_in[7];
    const float* Lambda = (const float*)d_in[8];
    float* out = (float*)d_out;
    (void)in_sizes; (void)n_in; (void)out_size; (void)ws_size;

    // ---- workspace layout (~110 MB) ----
    char* p = (char*)d_ws;
    auto alloc = [&](size_t bytes) { char* r = p; p += (bytes + 255) & ~255ULL; return r; };
    __hip_bfloat16* gpre  = (__hip_bfloat16*)alloc(8192ULL * 2048 * 2); // 32 MB
    __hip_bfloat16* ab    = (__hip_bfloat16*)alloc(8192ULL * 1024 * 2); // 16 MB
    __hip_bfloat16* bbp   = (__hip_bfloat16*)alloc(8200ULL * 1024 * 2); // 16.8 MB
    __hip_bfloat16* bcb   = (__hip_bfloat16*)alloc(8192ULL * 1024 * 2); // 16 MB (later zb)
    __hip_bfloat16* wbigb = (__hip_bfloat16*)alloc(1024ULL * 4096 * 2); // 8 MB
    __hip_bfloat16* xb    = (__hip_bfloat16*)alloc(8192ULL * 768 * 2);  // 12 MB
    __hip_bfloat16* w1b   = (__hip_bfloat16*)alloc(2048ULL * 768 * 2);  // 3 MB
    __hip_bfloat16* w_rgb = (__hip_bfloat16*)alloc(2048ULL * 1024 * 2); // 4 MB
    __hip_bfloat16* w_outb= (__hip_bfloat16*)alloc(768ULL * 1024 * 2);  // 1.5 MB
    float*          chv   = (float*)alloc(NC * 1024ULL * 4);
    float*          cav   = (float*)alloc(NC * 1024ULL * 4);
    __hip_bfloat16* zb    = bcb;   // overlay

    prep_kernel<<<PREP_TOT / 256, 256, 0, stream>>>(x, w1, w_rg, w_out, conv_w,
                                                    xb, w1b, w_rgb, w_outb, wbigb, bbp);

    // h = x @ w1.T + b1, fused split: ab = bf16(gelu), bbp = bf16 (rows +3)
    {
        dim3 grid(T_LEN / 128, 2048 / 128);
        gemm_mfma<false, 2><<<grid, 256, 0, stream>>>(xb, w1b, b1, ab, DM, DM, 2048, bbp);
    }

    // bc = causal conv as GEMM (M=8192, N=1024, K=4096) -> bf16
    {
        dim3 grid(T_LEN / 128, 1024 / 128);
        gemm_mfma<true, 1><<<grid, 256, 0, stream>>>(bbp, wbigb, nullptr, bcb, 4 * DR, DR, DR, nullptr);
    }

    // g_pre = bc @ w_rg.T + b_rg -> bf16
    {
        dim3 grid(T_LEN / 128, 2048 / 128);
        gemm_mfma<false, 1><<<grid, 256, 0, stream>>>(bcb, w_rgb, b_rg, gpre, DR, DR, 2048, nullptr);
    }

    // chunked scan with fused gates; z = ab*y -> bf16 (overlays bcb)
    {
        dim3 gs(NC, DR / 256);
        scan_pass1<<<gs, 256, 0, stream>>>(gpre, bcb, Lambda, chv, cav);
        scan_combine<<<DR / 256, 256, 0, stream>>>(chv, cav);
        scan_pass2<<<gs, 256, 0, stream>>>(gpre, bcb, Lambda, chv, ab, zb);
    }

    // out = z @ w_out.T + b_out -> fp32
    {
        dim3 grid(T_LEN / 128, DM / 128);
        gemm_mfma<false, 0><<<grid, 256, 0, stream>>>(zb, w_outb, b_out, out, DR, DR, DM, nullptr);
    }
}

// Round 6
// 364.720 us; speedup vs baseline: 1.2930x; 1.2930x over previous
//
#include <hip/hip_runtime.h>
#include <hip/hip_bf16.h>
#include <stdint.h>

// ---------------------------------------------------------------------------
// RG-LRU block: T=8192, D_MODEL=768, D_RNN=1024, KW=4.
// Round 6: back to r4 barrier structure; amortize the per-iteration barrier
// drain with more MFMA per barrier:
//  - conv kernel: stage the 131-row A halo ONCE per 32-col k-tile + 4 B shift
//    tiles; all 4 conv shifts computed per barrier (64 MFMA/wave/iter, 32 iters
//    instead of 128).
//  - dense GEMMs: BK=64 (32 MFMA/wave/iter).
//  - out-GEMM: BN=64 tiles (768 blocks -> 3/CU instead of 1.5/CU).
//  - XCD-aware grid + XOR bank swizzles + fused prep + bf16 g_pre retained.
// ---------------------------------------------------------------------------

#define T_LEN 8192
#define DM 768
#define DR 1024
#define NC 128   // scan chunks
#define CL 64    // chunk length

typedef __bf16 bf16x8 __attribute__((ext_vector_type(8)));
typedef float  f32x4  __attribute__((ext_vector_type(4)));

#define AS1 __attribute__((address_space(1)))
#define AS3 __attribute__((address_space(3)))

__device__ __forceinline__ void cp16_g2l(const void* g, void* l) {
    __builtin_amdgcn_global_load_lds((const AS1 void*)g, (AS3 void*)l, 16, 0, 0);
}

__device__ __forceinline__ float gelu_tanh(float x) {
    const float inner = 0.7978845608028654f * (x + 0.044715f * x * x * x);
    return 0.5f * x * (1.f + tanhf(inner));
}

// ---------------------------------------------------------------------------
// Dense GEMM: C[m,n] = sum_k A[m,k]*B[n,k] (+bias[n]).  BM=128, BK=64.
// A: M x K bf16 (lda), B: N x K bf16.  K % 64 == 0.
// LDS rows are 64 elements = 8 16B chunks; chunk slot s at row r holds global
// chunk s ^ (r & 7)  -> every wave64 ds_read_b128 is perfectly bank-balanced.
// EPI: 0 = fp32 +bias; 1 = bf16 +bias; 2 = split (gelu->Cv / shift->D2).
// ---------------------------------------------------------------------------
template<int BN, int EPI>
__global__ __launch_bounds__(256)
void gemm_mfma(const __hip_bfloat16* __restrict__ A,
               const __hip_bfloat16* __restrict__ B,
               const float* __restrict__ bias,
               void* __restrict__ Cv,
               int K, int lda, int N,
               __hip_bfloat16* __restrict__ D2)
{
    constexpr int NI = BN / 32;            // n-frags per wave (4 or 2)
    __shared__ __bf16 As[128 * 64];
    __shared__ __bf16 Bs[BN * 64];

    const int tid  = threadIdx.x;
    const int lane = tid & 63;
    const int wave = tid >> 6;
    const size_t m0 = (size_t)blockIdx.x * 128;   // XCD = blockIdx.x % 8
    const int    n0 = blockIdx.y * BN;
    const int wm = (wave >> 1) * 64;
    const int wn = (wave & 1) * (BN / 2);

    f32x4 acc[4][NI];
#pragma unroll
    for (int i = 0; i < 4; ++i)
#pragma unroll
        for (int j = 0; j < NI; ++j)
            acc[i][j] = f32x4{0.f, 0.f, 0.f, 0.f};

    const int frow = lane & 15;
    const int fq   = lane >> 4;

    for (int k0 = 0; k0 < K; k0 += 64) {
        __syncthreads();   // previous iteration's LDS reads complete
        // A tile: 128 rows x 8 chunks = 1024 chunks
#pragma unroll
        for (int q = 0; q < 4; ++q) {
            const int lin = q * 256 + tid;
            const int rr  = lin >> 3;
            const int gc  = (lin & 7) ^ (rr & 7);
            cp16_g2l(A + (m0 + rr) * (size_t)lda + k0 + gc * 8, &As[lin * 8]);
        }
        // B tile: BN rows x 8 chunks
#pragma unroll
        for (int q = 0; q < NI; ++q) {
            const int lin = q * 256 + tid;
            const int rr  = lin >> 3;
            const int gc  = (lin & 7) ^ (rr & 7);
            cp16_g2l(B + (size_t)(n0 + rr) * K + k0 + gc * 8, &Bs[lin * 8]);
        }
        __syncthreads();   // includes vmcnt(0) drain

#pragma unroll
        for (int ks = 0; ks < 2; ++ks) {
            bf16x8 af[4], bfr[NI];
#pragma unroll
            for (int mi = 0; mi < 4; ++mi) {
                const int R = wm + mi * 16 + frow;
                af[mi] = *(const bf16x8*)&As[R * 64 + (((ks * 4 + fq) ^ (R & 7)) * 8)];
            }
#pragma unroll
            for (int ni = 0; ni < NI; ++ni) {
                const int R = wn + ni * 16 + frow;
                bfr[ni] = *(const bf16x8*)&Bs[R * 64 + (((ks * 4 + fq) ^ (R & 7)) * 8)];
            }
#pragma unroll
            for (int mi = 0; mi < 4; ++mi)
#pragma unroll
                for (int ni = 0; ni < NI; ++ni)
                    acc[mi][ni] = __builtin_amdgcn_mfma_f32_16x16x32_bf16(
                        af[mi], bfr[ni], acc[mi][ni], 0, 0, 0);
        }
    }

    // C/D layout: col = lane&15, row = (lane>>4)*4 + reg
    const int er = fq * 4;
    const int ec = frow;
#pragma unroll
    for (int ni = 0; ni < NI; ++ni) {
        const int n = n0 + wn + ni * 16 + ec;
        const float bv = bias ? bias[n] : 0.f;
#pragma unroll
        for (int mi = 0; mi < 4; ++mi) {
#pragma unroll
            for (int r2 = 0; r2 < 4; ++r2) {
                const size_t m = m0 + wm + mi * 16 + er + r2;
                const float v = acc[mi][ni][r2] + bv;
                if (EPI == 0) {
                    ((float*)Cv)[m * (size_t)N + n] = v;
                } else if (EPI == 1) {
                    ((__hip_bfloat16*)Cv)[m * (size_t)N + n] = __float2bfloat16(v);
                } else {
                    if (n < 1024)
                        ((__hip_bfloat16*)Cv)[m * 1024 + n] = __float2bfloat16(gelu_tanh(v));
                    else
                        D2[(m + 3) * 1024 + (n - 1024)] = __float2bfloat16(v);
                }
            }
        }
    }
}

// ---------------------------------------------------------------------------
// Conv GEMM with shift reuse: bc[t,o] = sum_s sum_i W[o][s*1024+i]*bbp[t+s][i].
// Per 32-col k-tile: stage A halo (132 rows x 32 cols) ONCE + 4 B shift tiles
// (128 x 32 each), then 4 shifts x 16 MFMA per wave per barrier.  32 k-iters.
// 32-wide rows = 4 chunks; slot s at row r holds chunk s ^ ((r>>1)&3).
// ---------------------------------------------------------------------------
__global__ __launch_bounds__(256)
void conv_mfma(const __hip_bfloat16* __restrict__ bbp,
               const __hip_bfloat16* __restrict__ W,
               __hip_bfloat16* __restrict__ C)
{
    __shared__ __bf16 As[132 * 32];        // 8.25 KB halo tile
    __shared__ __bf16 Bs[4 * 128 * 32];    // 32 KB, 4 shift tiles

    const int tid  = threadIdx.x;
    const int lane = tid & 63;
    const int wave = tid >> 6;
    const size_t m0 = (size_t)blockIdx.x * 128;   // XCD = blockIdx.x % 8
    const int    n0 = blockIdx.y * 128;
    const int wm = (wave >> 1) * 64;
    const int wn = (wave & 1) * 64;

    f32x4 acc[4][4];
#pragma unroll
    for (int i = 0; i < 4; ++i)
#pragma unroll
        for (int j = 0; j < 4; ++j)
            acc[i][j] = f32x4{0.f, 0.f, 0.f, 0.f};

    const int frow = lane & 15;
    const int fq   = lane >> 4;

    for (int kc = 0; kc < 1024; kc += 32) {
        __syncthreads();
        // A halo: 132 rows x 4 chunks = 528 chunks (512 + 16 masked)
#pragma unroll
        for (int q = 0; q < 2; ++q) {
            const int lin = q * 256 + tid;
            const int rr  = lin >> 2;
            const int gc  = (lin & 3) ^ ((rr >> 1) & 3);
            cp16_g2l(bbp + (m0 + rr) * 1024 + kc + gc * 8, &As[lin * 8]);
        }
        if (tid < 16) {
            const int lin = 512 + tid;
            const int rr  = lin >> 2;
            const int gc  = (lin & 3) ^ ((rr >> 1) & 3);
            cp16_g2l(bbp + (m0 + rr) * 1024 + kc + gc * 8, &As[lin * 8]);
        }
        // B: 4 shift tiles, each 128 rows x 4 chunks = 512 chunks
#pragma unroll
        for (int s = 0; s < 4; ++s)
#pragma unroll
            for (int q = 0; q < 2; ++q) {
                const int lin = q * 256 + tid;
                const int rr  = lin >> 2;
                const int gc  = (lin & 3) ^ ((rr >> 1) & 3);
                cp16_g2l(W + (size_t)(n0 + rr) * 4096 + s * 1024 + kc + gc * 8,
                         &Bs[s * 4096 + lin * 8]);
            }
        __syncthreads();

#pragma unroll
        for (int s = 0; s < 4; ++s) {
            bf16x8 af[4], bfr[4];
#pragma unroll
            for (int mi = 0; mi < 4; ++mi) {
                const int R = wm + mi * 16 + frow + s;       // shifted row
                af[mi] = *(const bf16x8*)&As[R * 32 + ((fq ^ ((R >> 1) & 3)) * 8)];
            }
#pragma unroll
            for (int ni = 0; ni < 4; ++ni) {
                const int R = wn + ni * 16 + frow;
                bfr[ni] = *(const bf16x8*)&Bs[s * 4096 + R * 32 + ((fq ^ ((R >> 1) & 3)) * 8)];
            }
#pragma unroll
            for (int mi = 0; mi < 4; ++mi)
#pragma unroll
                for (int ni = 0; ni < 4; ++ni)
                    acc[mi][ni] = __builtin_amdgcn_mfma_f32_16x16x32_bf16(
                        af[mi], bfr[ni], acc[mi][ni], 0, 0, 0);
        }
    }

    const int er = fq * 4;
    const int ec = frow;
#pragma unroll
    for (int ni = 0; ni < 4; ++ni) {
        const int n = n0 + wn + ni * 16 + ec;
#pragma unroll
        for (int mi = 0; mi < 4; ++mi)
#pragma unroll
            for (int r2 = 0; r2 < 4; ++r2) {
                const size_t m = m0 + wm + mi * 16 + er + r2;
                C[m * 1024 + n] = __float2bfloat16(acc[mi][ni][r2]);
            }
    }
}

// One prep kernel: xb, w1b, w_rgb, w_outb conversions + conv repack + bbp pad zero.
#define PREP_X   6291456            // 8192*768
#define PREP_W1  (PREP_X + 1572864) // + 2048*768
#define PREP_WRG (PREP_W1 + 2097152)// + 2048*1024
#define PREP_WO  (PREP_WRG + 786432)// + 768*1024
#define PREP_CW  (PREP_WO + 4194304)// + 1024*4096
#define PREP_TOT (PREP_CW + 3072)   // + pad rows
__global__ void prep_kernel(const float* __restrict__ x, const float* __restrict__ w1,
                            const float* __restrict__ w_rg, const float* __restrict__ w_out,
                            const float* __restrict__ conv_w,
                            __hip_bfloat16* __restrict__ xb, __hip_bfloat16* __restrict__ w1b,
                            __hip_bfloat16* __restrict__ w_rgb, __hip_bfloat16* __restrict__ w_outb,
                            __hip_bfloat16* __restrict__ wbigb, __hip_bfloat16* __restrict__ bbp)
{
    const int idx = blockIdx.x * 256 + threadIdx.x;
    if (idx < PREP_X) {
        xb[idx] = __float2bfloat16(x[idx]);
    } else if (idx < PREP_W1) {
        const int i = idx - PREP_X;  w1b[i] = __float2bfloat16(w1[i]);
    } else if (idx < PREP_WRG) {
        const int i = idx - PREP_W1; w_rgb[i] = __float2bfloat16(w_rg[i]);
    } else if (idx < PREP_WO) {
        const int i = idx - PREP_WRG; w_outb[i] = __float2bfloat16(w_out[i]);
    } else if (idx < PREP_CW) {
        const int n = idx - PREP_WO;
        const int o = n >> 12, r = n & 4095, k = r >> 10, i = r & 1023;
        wbigb[n] = __float2bfloat16(conv_w[o * 4096 + i * 4 + k]);
    } else {
        bbp[idx - PREP_CW] = __float2bfloat16(0.f);
    }
}

// Gates recomputed inline from g_pre (T x 2048 bf16) + bc (bf16):
__global__ void scan_pass1(const __hip_bfloat16* __restrict__ gp,
                           const __hip_bfloat16* __restrict__ bc,
                           const float* __restrict__ Lambda,
                           float* __restrict__ ch, float* __restrict__ ca)
{
    const int c = blockIdx.y * 256 + threadIdx.x;
    const int j = blockIdx.x;
    const float cl = -8.f * log1pf(expf(Lambda[c]));
    float h = 0.f, ap = 1.f;
    const int t0 = j * CL;
    for (int tt = 0; tt < CL; ++tt) {
        const int t = t0 + tt;
        const long gi = (long)t * 2048 + c;
        const float ig = 1.f / (1.f + expf(-__bfloat162float(gp[gi])));
        const float rg = 1.f / (1.f + expf(-__bfloat162float(gp[gi + 1024])));
        const float a  = expf(cl * rg);
        const float gx = sqrtf(fmaxf(0.f, 1.f - a * a)) * ig *
                         __bfloat162float(bc[(long)t * 1024 + c]);
        h  = fmaf(a, h, gx);
        ap *= a;
    }
    ch[j * 1024 + c] = h;
    ca[j * 1024 + c] = ap;
}

__global__ void scan_combine(float* __restrict__ ch, const float* __restrict__ ca)
{
    const int c = blockIdx.x * 256 + threadIdx.x;
    float carry = 0.f;
    for (int j = 0; j < NC; ++j) {
        const float hj = ch[j * 1024 + c];
        const float aj = ca[j * 1024 + c];
        ch[j * 1024 + c] = carry;
        carry = fmaf(aj, carry, hj);
    }
}

// Rescan with carry; z = ab * y -> bf16 (zb aliases bc: same-element RMW per thread).
__global__ void scan_pass2(const __hip_bfloat16* __restrict__ gp, const __hip_bfloat16* bc,
                           const float* __restrict__ Lambda,
                           const float* __restrict__ carry_in,
                           const __hip_bfloat16* __restrict__ ab,
                           __hip_bfloat16* zb)
{
    const int c = blockIdx.y * 256 + threadIdx.x;
    const int j = blockIdx.x;
    const float cl = -8.f * log1pf(expf(Lambda[c]));
    float h = carry_in[j * 1024 + c];
    const int t0 = j * CL;
    for (int tt = 0; tt < CL; ++tt) {
        const int t = t0 + tt;
        const long gi = (long)t * 2048 + c;
        const long bi = (long)t * 1024 + c;
        const float ig = 1.f / (1.f + expf(-__bfloat162float(gp[gi])));
        const float rg = 1.f / (1.f + expf(-__bfloat162float(gp[gi + 1024])));
        const float a  = expf(cl * rg);
        const float gx = sqrtf(fmaxf(0.f, 1.f - a * a)) * ig * __bfloat162float(bc[bi]);
        h = fmaf(a, h, gx);
        zb[bi] = __float2bfloat16(__bfloat162float(ab[bi]) * h);
    }
}

extern "C" void kernel_launch(void* const* d_in, const int* in_sizes, int n_in,
                              void* d_out, int out_size, void* d_ws, size_t ws_size,
                              hipStream_t stream)
{
    const float* x      = (const float*)d_in[0];
    const float* w1     = (const float*)d_in[1];
    const float* b1     = (const float*)d_in[2];
    const float* conv_w = (const float*)d_in[3];
    const float* w_rg   = (const float*)d_in[4];
    const float* b_rg   = (const float*)d_in[5];
    const float* w_out  = (const float*)d_in[6];
    const float* b_out  = (const float*)d_in[7];
    const float* Lambda = (const float*)d_in[8];
    float* out = (float*)d_out;
    (void)in_sizes; (void)n_in; (void)out_size; (void)ws_size;

    // ---- workspace layout (~110 MB) ----
    char* p = (char*)d_ws;
    auto alloc = [&](size_t bytes) { char* r = p; p += (bytes + 255) & ~255ULL; return r; };
    __hip_bfloat16* gpre  = (__hip_bfloat16*)alloc(8192ULL * 2048 * 2); // 32 MB
    __hip_bfloat16* ab    = (__hip_bfloat16*)alloc(8192ULL * 1024 * 2); // 16 MB
    __hip_bfloat16* bbp   = (__hip_bfloat16*)alloc(8200ULL * 1024 * 2); // 16.8 MB
    __hip_bfloat16* bcb   = (__hip_bfloat16*)alloc(8192ULL * 1024 * 2); // 16 MB (later zb)
    __hip_bfloat16* wbigb = (__hip_bfloat16*)alloc(1024ULL * 4096 * 2); // 8 MB
    __hip_bfloat16* xb    = (__hip_bfloat16*)alloc(8192ULL * 768 * 2);  // 12 MB
    __hip_bfloat16* w1b   = (__hip_bfloat16*)alloc(2048ULL * 768 * 2);  // 3 MB
    __hip_bfloat16* w_rgb = (__hip_bfloat16*)alloc(2048ULL * 1024 * 2); // 4 MB
    __hip_bfloat16* w_outb= (__hip_bfloat16*)alloc(768ULL * 1024 * 2);  // 1.5 MB
    float*          chv   = (float*)alloc(NC * 1024ULL * 4);
    float*          cav   = (float*)alloc(NC * 1024ULL * 4);
    __hip_bfloat16* zb    = bcb;   // overlay

    prep_kernel<<<PREP_TOT / 256, 256, 0, stream>>>(x, w1, w_rg, w_out, conv_w,
                                                    xb, w1b, w_rgb, w_outb, wbigb, bbp);

    // h = x @ w1.T + b1, fused split: ab = bf16(gelu), bbp = bf16 (rows +3)
    {
        dim3 grid(T_LEN / 128, 2048 / 128);
        gemm_mfma<128, 2><<<grid, 256, 0, stream>>>(xb, w1b, b1, ab, DM, DM, 2048, bbp);
    }

    // bc = causal conv (shift-reuse kernel) -> bf16
    {
        dim3 grid(T_LEN / 128, 1024 / 128);
        conv_mfma<<<grid, 256, 0, stream>>>(bbp, wbigb, bcb);
    }

    // g_pre = bc @ w_rg.T + b_rg -> bf16
    {
        dim3 grid(T_LEN / 128, 2048 / 128);
        gemm_mfma<128, 1><<<grid, 256, 0, stream>>>(bcb, w_rgb, b_rg, gpre, DR, DR, 2048, nullptr);
    }

    // chunked scan with fused gates; z = ab*y -> bf16 (overlays bcb)
    {
        dim3 gs(NC, DR / 256);
        scan_pass1<<<gs, 256, 0, stream>>>(gpre, bcb, Lambda, chv, cav);
        scan_combine<<<DR / 256, 256, 0, stream>>>(chv, cav);
        scan_pass2<<<gs, 256, 0, stream>>>(gpre, bcb, Lambda, chv, ab, zb);
    }

    // out = z @ w_out.T + b_out -> fp32  (BN=64 tiles: 768 blocks -> 3/CU)
    {
        dim3 grid(T_LEN / 128, DM / 64);
        gemm_mfma<64, 0><<<grid, 256, 0, stream>>>(zb, w_outb, b_out, out, DR, DR, DM, nullptr);
    }
}